// Round 2
// baseline (342.570 us; speedup 1.0000x reference)
//
#include <hip/hip_runtime.h>

#define DD   32     // input size
#define HH   256    // hidden size
#define BB   4096   // batch
#define EPSF 1e-12f

// Degrees: deg_in[i] = i+1 ; deg_h[h] = (h % 31) + 1.
// h0[h]  = relu(b0[h] + sum_{i <= deg_h[h]-1} y_i W0[i,h])
// h1[h'] = relu(b1[h'] + sum_{deg_h[h] <= deg_h[h']} h0[h] W1[h,h'])
// out[d] = b2[d] + sum_{deg_h[h'] <= d} h1[h'] W2[h',d]
// Sequential forward substitution: at step d, hiddens with deg==d finalize.
// One wave per row (RR=1): 4096 blocks -> 16 waves/CU -> 4 waves/SIMD for
// latency hiding (R1 showed VALUBusy=31% at 1 wave/SIMD).

__global__ __launch_bounds__(64, 4) void made_inv(
    const float* __restrict__ x,
    const float* __restrict__ muW0, const float* __restrict__ mub0,
    const float* __restrict__ muW1, const float* __restrict__ mub1,
    const float* __restrict__ muW2, const float* __restrict__ mub2,
    const float* __restrict__ lvW0, const float* __restrict__ lvb0,
    const float* __restrict__ lvW1, const float* __restrict__ lvb1,
    const float* __restrict__ lvW2, const float* __restrict__ lvb2,
    float* __restrict__ out)
{
    const int lane = threadIdx.x;      // 0..63
    const int row  = blockIdx.x;       // one row per (single-wave) block
    const int hb   = lane << 2;        // 4 hidden slots per lane

    int deg[4];
    #pragma unroll
    for (int s = 0; s < 4; ++s) deg[s] = ((hb + s) % 31) + 1;

    const float* Wp0[2] = {muW0, lvW0};
    const float* Bp0[2] = {mub0, lvb0};
    const float* Wp1[2] = {muW1, lvW1};
    const float* Bp1[2] = {mub1, lvb1};
    const float* Wp2[2] = {muW2, lvW2};

    // per-lane state: [net][slot]
    float h0pre[2][4];
    float h1pre[2][4];
    float r1   [2][4];   // relu(h1) snapshot at finalize; 0 until then
    float yprev = 0.f;
    float lsum  = 0.f;

    #pragma unroll
    for (int n = 0; n < 2; ++n) {
        const float4 b0v = *reinterpret_cast<const float4*>(Bp0[n] + hb);
        const float4 b1v = *reinterpret_cast<const float4*>(Bp1[n] + hb);
        h0pre[n][0] = b0v.x; h0pre[n][1] = b0v.y;
        h0pre[n][2] = b0v.z; h0pre[n][3] = b0v.w;
        h1pre[n][0] = b1v.x; h1pre[n][1] = b1v.y;
        h1pre[n][2] = b1v.z; h1pre[n][3] = b1v.w;
        #pragma unroll
        for (int s = 0; s < 4; ++s) r1[n][s] = 0.f;
    }

    // broadcast scratch for newly-finalized relu(h0): [net][k<=9 (pad 12)]
    __shared__ float lds_a[2][12];

    const float* xrow = x + row * DD;

    for (int d = 0; d < DD; ++d) {
        if (d >= 1) {
            // ---- h0pre += y_{d-1} * W0[d-1, :]  (unpredicated: mask-safe)
            #pragma unroll
            for (int n = 0; n < 2; ++n) {
                const float4 w0 = *reinterpret_cast<const float4*>(
                    Wp0[n] + (d - 1) * HH + hb);
                h0pre[n][0] = fmaf(yprev, w0.x, h0pre[n][0]);
                h0pre[n][1] = fmaf(yprev, w0.y, h0pre[n][1]);
                h0pre[n][2] = fmaf(yprev, w0.z, h0pre[n][2]);
                h0pre[n][3] = fmaf(yprev, w0.w, h0pre[n][3]);
            }
            // ---- finalize h0 with deg==d -> LDS (h = d-1 + 31k)
            #pragma unroll
            for (int s = 0; s < 4; ++s)
                if (deg[s] == d) {
                    const int k = (hb + s - (d - 1)) / 31;
                    lds_a[0][k] = fmaxf(h0pre[0][s], 0.f);
                    lds_a[1][k] = fmaxf(h0pre[1][s], 0.f);
                }
            __syncthreads();

            // ---- h1pre += relu(h0[deg==d]) * W1[deg==d, :]
            const bool nine = (d <= 8);   // k=8 exists only for d<=8
            #pragma unroll
            for (int n = 0; n < 2; ++n) {
                const float* W1p = Wp1[n] + (size_t)(d - 1) * HH + hb;
                float4 w1v[9];
                #pragma unroll
                for (int k = 0; k < 8; ++k)
                    w1v[k] = *reinterpret_cast<const float4*>(W1p + k * 31 * HH);
                if (nine)
                    w1v[8] = *reinterpret_cast<const float4*>(W1p + 8 * 31 * HH);

                const float4 a03 = *reinterpret_cast<const float4*>(&lds_a[n][0]);
                const float4 a47 = *reinterpret_cast<const float4*>(&lds_a[n][4]);
                const float  av[8] = {a03.x, a03.y, a03.z, a03.w,
                                      a47.x, a47.y, a47.z, a47.w};
                #pragma unroll
                for (int k = 0; k < 8; ++k) {
                    h1pre[n][0] = fmaf(av[k], w1v[k].x, h1pre[n][0]);
                    h1pre[n][1] = fmaf(av[k], w1v[k].y, h1pre[n][1]);
                    h1pre[n][2] = fmaf(av[k], w1v[k].z, h1pre[n][2]);
                    h1pre[n][3] = fmaf(av[k], w1v[k].w, h1pre[n][3]);
                }
                if (nine) {
                    const float a8 = lds_a[n][8];
                    h1pre[n][0] = fmaf(a8, w1v[8].x, h1pre[n][0]);
                    h1pre[n][1] = fmaf(a8, w1v[8].y, h1pre[n][1]);
                    h1pre[n][2] = fmaf(a8, w1v[8].z, h1pre[n][2]);
                    h1pre[n][3] = fmaf(a8, w1v[8].w, h1pre[n][3]);
                }
            }
            // ---- snapshot relu(h1) for slots finalizing now
            #pragma unroll
            for (int s = 0; s < 4; ++s)
                if (deg[s] == d) {
                    r1[0][s] = fmaxf(h1pre[0][s], 0.f);
                    r1[1][s] = fmaxf(h1pre[1][s], 0.f);
                }
            __syncthreads();   // LDS reads of step d done before step d+1 writes
        }

        // ---- output d: reduce r1 * W2[:, d] over all 256 hiddens
        float red[2];
        #pragma unroll
        for (int n = 0; n < 2; ++n) {
            const float* W2p = Wp2[n] + hb * DD + d;
            float p;
            p = r1[n][0] * W2p[0];
            p = fmaf(r1[n][1], W2p[DD],     p);
            p = fmaf(r1[n][2], W2p[2 * DD], p);
            p = fmaf(r1[n][3], W2p[3 * DD], p);
            red[n] = p;
        }
        #pragma unroll
        for (int m = 1; m < 64; m <<= 1) {
            red[0] += __shfl_xor(red[0], m, 64);
            red[1] += __shfl_xor(red[1], m, 64);
        }

        const float mu     = red[0] + mub2[d];
        const float logstd = 0.5f * (red[1] + lvb2[d]);
        lsum += logstd;
        const float denom = __expf(logstd) + EPSF;
        const float yd = (xrow[d] - mu) / denom;
        yprev = yd;
        if (lane == 0) out[row * DD + d] = yd;
    }

    if (lane == 0) out[BB * DD + row] = lsum;
}

extern "C" void kernel_launch(void* const* d_in, const int* in_sizes, int n_in,
                              void* d_out, int out_size, void* d_ws, size_t ws_size,
                              hipStream_t stream) {
    const float* x    = (const float*)d_in[0];
    const float* muW0 = (const float*)d_in[1];
    const float* mub0 = (const float*)d_in[2];
    const float* muW1 = (const float*)d_in[3];
    const float* mub1 = (const float*)d_in[4];
    const float* muW2 = (const float*)d_in[5];
    const float* mub2 = (const float*)d_in[6];
    const float* lvW0 = (const float*)d_in[7];
    const float* lvb0 = (const float*)d_in[8];
    const float* lvW1 = (const float*)d_in[9];
    const float* lvb1 = (const float*)d_in[10];
    const float* lvW2 = (const float*)d_in[11];
    const float* lvb2 = (const float*)d_in[12];
    float* out = (float*)d_out;

    dim3 grid(BB);     // one row per single-wave block
    dim3 block(64);
    made_inv<<<grid, block, 0, stream>>>(x,
        muW0, mub0, muW1, mub1, muW2, mub2,
        lvW0, lvb0, lvW1, lvb1, lvW2, lvb2,
        out);
}

// Round 3
// 207.050 us; speedup vs baseline: 1.6545x; 1.6545x over previous
//
#include <hip/hip_runtime.h>

#define DD   32
#define HH   256
#define BB   4096
#define EPSF 1e-12f

// ---------------------------------------------------------------------------
// Degree-sorted layout.
// deg_h[h] = (h%31)+1. Counts: deg 1..8 -> 9 units, deg 9..31 -> 8 units.
// Sorted position p -> original h:
//   p < 72:  r = p/9, c = p%9,            h = r + 31c      (deg = r+1, 1..8)
//   p >= 72: q = p-72, r = 8+q/8, c = q%8, h = r + 31c     (deg = r+1, 9..31)
// Group deg==d occupies positions [OFF[d], OFF[d+1]).
// ---------------------------------------------------------------------------
__device__ constexpr int OFFT[33] = {
    0, 0, 9, 18, 27, 36, 45, 54, 63, 72, 80, 88, 96, 104, 112, 120, 128,
    136, 144, 152, 160, 168, 176, 184, 192, 200, 208, 216, 224, 232, 240,
    248, 256};

__device__ __forceinline__ int made_pi(int p) {
    return (p < 72) ? (p / 9) + 31 * (p % 9)
                    : (8 + (p - 72) / 8) + 31 * ((p - 72) % 8);
}

// ws float layout per net: W0s[32][256] | W1s[256][256] | W2Ts[32][256] | b0s[256] | b1s[256]
#define NW0   (DD * HH)                       // 8192
#define NW1   (HH * HH)                       // 65536
#define NW2   (DD * HH)                       // 8192
#define NETF  (NW0 + NW1 + NW2 + HH + HH)     // 82432 floats per net
#define WSNEED ((size_t)(2 * NETF) * 4)       // 659456 bytes

// ---------------------------------------------------------------------------
// Prep: permute/transpose weights into d_ws (sorted-degree order).
// grid = 512 blocks (net = blk>>8, sorted position p = blk&255), 64 threads.
// ---------------------------------------------------------------------------
__global__ void made_prep(
    const float* __restrict__ muW0, const float* __restrict__ mub0,
    const float* __restrict__ muW1, const float* __restrict__ mub1,
    const float* __restrict__ muW2,
    const float* __restrict__ lvW0, const float* __restrict__ lvb0,
    const float* __restrict__ lvW1, const float* __restrict__ lvb1,
    const float* __restrict__ lvW2,
    float* __restrict__ ws)
{
    const int t = threadIdx.x;           // 0..63
    const int p = blockIdx.x & 255;      // sorted position (output row)
    const int n = blockIdx.x >> 8;       // net: 0=mu, 1=lv
    const int h = made_pi(p);            // source hidden unit
    const float* W0 = n ? lvW0 : muW0;
    const float* W1 = n ? lvW1 : muW1;
    const float* W2 = n ? lvW2 : muW2;
    const float* b0 = n ? lvb0 : mub0;
    const float* b1 = n ? lvb1 : mub1;
    float* o = ws + (size_t)n * NETF;

    // W1 sorted: row p (coalesced writes), source row h with permuted columns
    for (int j = t; j < HH; j += 64)
        o[NW0 + p * HH + j] = W1[h * HH + made_pi(j)];
    if (t < DD) {
        o[t * HH + p]             = W0[t * HH + h];   // W0s[i][p]
        o[NW0 + NW1 + t * HH + p] = W2[h * DD + t];   // W2Ts[d][p]
    }
    if (t == 0) {
        o[NW0 + NW1 + NW2 + p]      = b0[h];
        o[NW0 + NW1 + NW2 + HH + p] = b1[h];
    }
}

// ---------------------------------------------------------------------------
// Main: 4 waves/block, 1 row/wave, no LDS, no barriers. Fully unrolled d-loop
// so finalize lanes/slots and exec-mask boundaries are compile-time constants.
// ---------------------------------------------------------------------------
__global__ __launch_bounds__(256, 4) void made_main(
    const float* __restrict__ ws, const float* __restrict__ x,
    const float* __restrict__ mub2, const float* __restrict__ lvb2,
    float* __restrict__ out)
{
    const int lane = threadIdx.x & 63;
    const int wv   = threadIdx.x >> 6;
    const int row  = (blockIdx.x << 2) + wv;
    const int c4   = lane << 2;

    const float* W0s[2] = {ws,              ws + NETF};
    const float* W1s[2] = {ws + NW0,        ws + NETF + NW0};
    const float* W2s[2] = {ws + NW0 + NW1,  ws + NETF + NW0 + NW1};
    const float* b0s[2] = {ws + NW0 + NW1 + NW2,      ws + NETF + NW0 + NW1 + NW2};
    const float* b1s[2] = {ws + NW0 + NW1 + NW2 + HH, ws + NETF + NW0 + NW1 + NW2 + HH};

    float h0pre[2][4], h1pre[2][4], r1[2][4];
    #pragma unroll
    for (int n = 0; n < 2; ++n) {
        const float4 v0 = *reinterpret_cast<const float4*>(b0s[n] + c4);
        const float4 v1 = *reinterpret_cast<const float4*>(b1s[n] + c4);
        h0pre[n][0] = v0.x; h0pre[n][1] = v0.y; h0pre[n][2] = v0.z; h0pre[n][3] = v0.w;
        h1pre[n][0] = v1.x; h1pre[n][1] = v1.y; h1pre[n][2] = v1.z; h1pre[n][3] = v1.w;
        #pragma unroll
        for (int s = 0; s < 4; ++s) r1[n][s] = 0.f;
    }

    // per-lane preloads of step-uniform scalars; broadcast via shfl(., d)
    const float bm = (lane < DD) ? mub2[lane] : 0.f;
    const float bl = (lane < DD) ? lvb2[lane] : 0.f;
    const float xv = (lane < DD) ? x[row * DD + lane] : 0.f;

    float yprev = 0.f, lsum = 0.f, ysave = 0.f;

    #pragma unroll
    for (int d = 0; d < DD; ++d) {
        const int nk = OFFT[d + 1] - OFFT[d];   // 9 (d<=8) or 8, 0 at d=0
        const int ls = OFFT[d] >> 2;            // first possibly-active lane

        if (d >= 1) {
            // ---- h0pre += y_{d-1} * W0s[d-1, :] on non-retired lanes
            if (lane >= ls) {
                const float4 a = *reinterpret_cast<const float4*>(W0s[0] + (d - 1) * HH + c4);
                const float4 b = *reinterpret_cast<const float4*>(W0s[1] + (d - 1) * HH + c4);
                h0pre[0][0] = fmaf(yprev, a.x, h0pre[0][0]);
                h0pre[0][1] = fmaf(yprev, a.y, h0pre[0][1]);
                h0pre[0][2] = fmaf(yprev, a.z, h0pre[0][2]);
                h0pre[0][3] = fmaf(yprev, a.w, h0pre[0][3]);
                h1pre[0][0] = h1pre[0][0];  // keep structure simple for regalloc
                h0pre[1][0] = fmaf(yprev, b.x, h0pre[1][0]);
                h0pre[1][1] = fmaf(yprev, b.y, h0pre[1][1]);
                h0pre[1][2] = fmaf(yprev, b.z, h0pre[1][2]);
                h0pre[1][3] = fmaf(yprev, b.w, h0pre[1][3]);
            }

            // ---- broadcast relu(h0) of finalizing positions (compile-time lanes/slots)
            float av0[9], av1[9];
            #pragma unroll
            for (int k = 0; k < nk; ++k) {
                const int P  = OFFT[d] + k;
                const int sl = P >> 2;
                const int ss = P & 3;
                av0[k] = fmaxf(__shfl(h0pre[0][ss], sl, 64), 0.f);
                av1[k] = fmaxf(__shfl(h0pre[1][ss], sl, 64), 0.f);
            }

            // ---- h1pre += av * W1s[rows deg==d, cols] on non-retired lanes
            if (lane >= ls) {
                {
                    const float* W1p = W1s[0] + OFFT[d] * HH + c4;
                    #pragma unroll
                    for (int k = 0; k < nk; ++k) {
                        const float4 w = *reinterpret_cast<const float4*>(W1p + k * HH);
                        h1pre[0][0] = fmaf(av0[k], w.x, h1pre[0][0]);
                        h1pre[0][1] = fmaf(av0[k], w.y, h1pre[0][1]);
                        h1pre[0][2] = fmaf(av0[k], w.z, h1pre[0][2]);
                        h1pre[0][3] = fmaf(av0[k], w.w, h1pre[0][3]);
                    }
                }
                {
                    const float* W1p = W1s[1] + OFFT[d] * HH + c4;
                    #pragma unroll
                    for (int k = 0; k < nk; ++k) {
                        const float4 w = *reinterpret_cast<const float4*>(W1p + k * HH);
                        h1pre[1][0] = fmaf(av1[k], w.x, h1pre[1][0]);
                        h1pre[1][1] = fmaf(av1[k], w.y, h1pre[1][1]);
                        h1pre[1][2] = fmaf(av1[k], w.z, h1pre[1][2]);
                        h1pre[1][3] = fmaf(av1[k], w.w, h1pre[1][3]);
                    }
                }
            }

            // ---- snapshot relu(h1) for positions finalizing now
            #pragma unroll
            for (int k = 0; k < nk; ++k) {
                const int P = OFFT[d] + k;
                if (lane == (P >> 2)) {
                    r1[0][P & 3] = fmaxf(h1pre[0][P & 3], 0.f);
                    r1[1][P & 3] = fmaxf(h1pre[1][P & 3], 0.f);
                }
            }
        }

        // ---- out[d]: reduce r1 * W2T[d, :] (only prefix lanes can be nonzero)
        float red0 = 0.f, red1 = 0.f;
        if (lane <= ((OFFT[d + 1] - 1) >> 2)) {   // d=0: -1 -> all skip
            const float4 wm = *reinterpret_cast<const float4*>(W2s[0] + d * HH + c4);
            const float4 wl = *reinterpret_cast<const float4*>(W2s[1] + d * HH + c4);
            red0 = fmaf(r1[0][0], wm.x, fmaf(r1[0][1], wm.y,
                   fmaf(r1[0][2], wm.z, r1[0][3] * wm.w)));
            red1 = fmaf(r1[1][0], wl.x, fmaf(r1[1][1], wl.y,
                   fmaf(r1[1][2], wl.z, r1[1][3] * wl.w)));
        }
        #pragma unroll
        for (int m = 1; m < 64; m <<= 1) {
            red0 += __shfl_xor(red0, m, 64);
            red1 += __shfl_xor(red1, m, 64);
        }

        const float mu  = red0 + __shfl(bm, d, 64);
        const float ls2 = 0.5f * (red1 + __shfl(bl, d, 64));
        lsum += ls2;
        const float yd = (__shfl(xv, d, 64) - mu) / (__expf(ls2) + EPSF);
        yprev = yd;
        if (lane == d) ysave = yd;
    }

    if (lane < DD) out[row * DD + lane] = ysave;       // coalesced 128B/row
    if (lane == 0) out[BB * DD + row] = lsum;
}

// ---------------------------------------------------------------------------
// Fallback (R1 kernel, RR=4, single wave/block) if ws is too small.
// ---------------------------------------------------------------------------
__global__ __launch_bounds__(64, 1) void made_inv_fb(
    const float* __restrict__ x,
    const float* __restrict__ muW0, const float* __restrict__ mub0,
    const float* __restrict__ muW1, const float* __restrict__ mub1,
    const float* __restrict__ muW2, const float* __restrict__ mub2,
    const float* __restrict__ lvW0, const float* __restrict__ lvb0,
    const float* __restrict__ lvW1, const float* __restrict__ lvb1,
    const float* __restrict__ lvW2, const float* __restrict__ lvb2,
    float* __restrict__ out)
{
    const int lane    = threadIdx.x;
    const int rowBase = blockIdx.x * 4;
    const int hb      = lane << 2;

    int deg[4];
    #pragma unroll
    for (int s = 0; s < 4; ++s) deg[s] = ((hb + s) % 31) + 1;

    const float* Wp0[2] = {muW0, lvW0};
    const float* Bp0[2] = {mub0, lvb0};
    const float* Wp1[2] = {muW1, lvW1};
    const float* Bp1[2] = {mub1, lvb1};
    const float* Wp2[2] = {muW2, lvW2};

    float h0pre[2][4][4], h1pre[2][4][4], r1[2][4][4], yprev[4], lsum[4];
    #pragma unroll
    for (int n = 0; n < 2; ++n) {
        const float4 b0v = *reinterpret_cast<const float4*>(Bp0[n] + hb);
        const float4 b1v = *reinterpret_cast<const float4*>(Bp1[n] + hb);
        const float b0a[4] = {b0v.x, b0v.y, b0v.z, b0v.w};
        const float b1a[4] = {b1v.x, b1v.y, b1v.z, b1v.w};
        #pragma unroll
        for (int s = 0; s < 4; ++s)
            #pragma unroll
            for (int r = 0; r < 4; ++r) {
                h0pre[n][s][r] = b0a[s]; h1pre[n][s][r] = b1a[s]; r1[n][s][r] = 0.f;
            }
    }
    #pragma unroll
    for (int r = 0; r < 4; ++r) { yprev[r] = 0.f; lsum[r] = 0.f; }

    __shared__ float lds_a[2][4][12];

    for (int d = 0; d < DD; ++d) {
        if (d >= 1) {
            #pragma unroll
            for (int n = 0; n < 2; ++n) {
                const float4 w0 = *reinterpret_cast<const float4*>(Wp0[n] + (d - 1) * HH + hb);
                const float w0a[4] = {w0.x, w0.y, w0.z, w0.w};
                #pragma unroll
                for (int s = 0; s < 4; ++s)
                    #pragma unroll
                    for (int r = 0; r < 4; ++r)
                        h0pre[n][s][r] = fmaf(yprev[r], w0a[s], h0pre[n][s][r]);
            }
            #pragma unroll
            for (int n = 0; n < 2; ++n)
                #pragma unroll
                for (int s = 0; s < 4; ++s)
                    if (deg[s] == d) {
                        const int k = (hb + s - (d - 1)) / 31;
                        #pragma unroll
                        for (int r = 0; r < 4; ++r)
                            lds_a[n][r][k] = fmaxf(h0pre[n][s][r], 0.f);
                    }
            __syncthreads();
            const bool nine = (d <= 8);
            #pragma unroll
            for (int n = 0; n < 2; ++n) {
                const float* W1p = Wp1[n] + (size_t)(d - 1) * HH + hb;
                float4 w1v[9];
                #pragma unroll
                for (int k = 0; k < 8; ++k)
                    w1v[k] = *reinterpret_cast<const float4*>(W1p + k * 31 * HH);
                if (nine) w1v[8] = *reinterpret_cast<const float4*>(W1p + 8 * 31 * HH);
                #pragma unroll
                for (int r = 0; r < 4; ++r) {
                    const float4 a03 = *reinterpret_cast<const float4*>(&lds_a[n][r][0]);
                    const float4 a47 = *reinterpret_cast<const float4*>(&lds_a[n][r][4]);
                    const float av[8] = {a03.x, a03.y, a03.z, a03.w, a47.x, a47.y, a47.z, a47.w};
                    #pragma unroll
                    for (int k = 0; k < 8; ++k) {
                        const float wk[4] = {w1v[k].x, w1v[k].y, w1v[k].z, w1v[k].w};
                        #pragma unroll
                        for (int s = 0; s < 4; ++s)
                            h1pre[n][s][r] = fmaf(av[k], wk[s], h1pre[n][s][r]);
                    }
                    if (nine) {
                        const float a8 = lds_a[n][r][8];
                        const float wk[4] = {w1v[8].x, w1v[8].y, w1v[8].z, w1v[8].w};
                        #pragma unroll
                        for (int s = 0; s < 4; ++s)
                            h1pre[n][s][r] = fmaf(a8, wk[s], h1pre[n][s][r]);
                    }
                }
            }
            #pragma unroll
            for (int n = 0; n < 2; ++n)
                #pragma unroll
                for (int s = 0; s < 4; ++s)
                    if (deg[s] == d)
                        #pragma unroll
                        for (int r = 0; r < 4; ++r)
                            r1[n][s][r] = fmaxf(h1pre[n][s][r], 0.f);
            __syncthreads();
        }
        float w2v[2][4];
        #pragma unroll
        for (int n = 0; n < 2; ++n)
            #pragma unroll
            for (int s = 0; s < 4; ++s)
                w2v[n][s] = Wp2[n][(hb + s) * DD + d];
        float red[2][4];
        #pragma unroll
        for (int n = 0; n < 2; ++n)
            #pragma unroll
            for (int r = 0; r < 4; ++r) {
                float p = 0.f;
                #pragma unroll
                for (int s = 0; s < 4; ++s) p = fmaf(r1[n][s][r], w2v[n][s], p);
                red[n][r] = p;
            }
        #pragma unroll
        for (int m = 1; m < 64; m <<= 1)
            #pragma unroll
            for (int n = 0; n < 2; ++n)
                #pragma unroll
                for (int r = 0; r < 4; ++r)
                    red[n][r] += __shfl_xor(red[n][r], m, 64);
        const float b2m = mub2[d], b2l = lvb2[d];
        #pragma unroll
        for (int r = 0; r < 4; ++r) {
            const float mu = red[0][r] + b2m;
            const float logstd = 0.5f * (red[1][r] + b2l);
            lsum[r] += logstd;
            const float yd = (x[(rowBase + r) * DD + d] - mu) / (__expf(logstd) + EPSF);
            yprev[r] = yd;
            if (lane == 0) out[(rowBase + r) * DD + d] = yd;
        }
    }
    if (lane == 0)
        #pragma unroll
        for (int r = 0; r < 4; ++r) out[BB * DD + rowBase + r] = lsum[r];
}

extern "C" void kernel_launch(void* const* d_in, const int* in_sizes, int n_in,
                              void* d_out, int out_size, void* d_ws, size_t ws_size,
                              hipStream_t stream) {
    const float* x    = (const float*)d_in[0];
    const float* muW0 = (const float*)d_in[1];
    const float* mub0 = (const float*)d_in[2];
    const float* muW1 = (const float*)d_in[3];
    const float* mub1 = (const float*)d_in[4];
    const float* muW2 = (const float*)d_in[5];
    const float* mub2 = (const float*)d_in[6];
    const float* lvW0 = (const float*)d_in[7];
    const float* lvb0 = (const float*)d_in[8];
    const float* lvW1 = (const float*)d_in[9];
    const float* lvb1 = (const float*)d_in[10];
    const float* lvW2 = (const float*)d_in[11];
    const float* lvb2 = (const float*)d_in[12];
    float* out = (float*)d_out;

    if (ws_size >= WSNEED) {
        float* ws = (float*)d_ws;
        made_prep<<<dim3(512), dim3(64), 0, stream>>>(
            muW0, mub0, muW1, mub1, muW2,
            lvW0, lvb0, lvW1, lvb1, lvW2, ws);
        made_main<<<dim3(BB / 4), dim3(256), 0, stream>>>(ws, x, mub2, lvb2, out);
    } else {
        made_inv_fb<<<dim3(BB / 4), dim3(64), 0, stream>>>(x,
            muW0, mub0, muW1, mub1, muW2, mub2,
            lvW0, lvb0, lvW1, lvb1, lvW2, lvb2, out);
    }
}

// Round 4
// 163.288 us; speedup vs baseline: 2.0980x; 1.2680x over previous
//
#include <hip/hip_runtime.h>

#define DD   32
#define HH   256
#define BB   4096
#define RR   2      // rows per wave
#define EPSF 1e-12f

// ---------------------------------------------------------------------------
// Degree-sorted layout. deg_h[h] = (h%31)+1. Counts: deg 1..8 -> 9, 9..31 -> 8.
// Sorted position p -> original h:
//   p < 72:  h = (p/9) + 31*(p%9)          (deg = p/9+1, 1..8)
//   p >= 72: h = (8+(p-72)/8) + 31*((p-72)%8)
// Group deg==d occupies sorted positions [OFF(d), OFF(d+1)),
//   OFF(d) = (d<=9) ? 9*(d-1) : 8*d   (valid for d>=1; OFF(1)=0, OFF(32)=256)
// ---------------------------------------------------------------------------
__device__ __forceinline__ int made_pi(int p) {
    return (p < 72) ? (p / 9) + 31 * (p % 9)
                    : (8 + (p - 72) / 8) + 31 * ((p - 72) % 8);
}
__device__ __forceinline__ int made_off(int d) {   // d >= 1
    return (d <= 9) ? 9 * (d - 1) : 8 * d;
}

// ws float layout per net: W0s[32][256] | W1s[256][256] | W2Ts[32][256] | b0s[256] | b1s[256]
#define NW0   (DD * HH)
#define NW1   (HH * HH)
#define NW2   (DD * HH)
#define NETF  (NW0 + NW1 + NW2 + HH + HH)
#define WSNEED ((size_t)(2 * NETF) * 4)

// ---------------------------------------------------------------------------
// Prep (coalesced): blocks 0..511 permute W1 rows via LDS staging;
// blocks 512..639 handle W0s rows (LDS-staged) and W2T rows.
// ---------------------------------------------------------------------------
__global__ void made_prep(
    const float* __restrict__ muW0, const float* __restrict__ mub0,
    const float* __restrict__ muW1, const float* __restrict__ mub1,
    const float* __restrict__ muW2,
    const float* __restrict__ lvW0, const float* __restrict__ lvb0,
    const float* __restrict__ lvW1, const float* __restrict__ lvb1,
    const float* __restrict__ lvW2,
    float* __restrict__ ws)
{
    const int t = threadIdx.x;           // 0..63
    const int b = blockIdx.x;
    __shared__ float rowbuf[HH];

    if (b < 512) {
        const int n = b >> 8, p = b & 255;
        const int h = made_pi(p);
        const float* W1 = n ? lvW1 : muW1;
        float* o = ws + (size_t)n * NETF;
        // coalesced read of source row h
        *reinterpret_cast<float4*>(&rowbuf[4 * t]) =
            *reinterpret_cast<const float4*>(W1 + h * HH + 4 * t);
        __syncthreads();
        // permuted gather from LDS, coalesced write of sorted row p
        float4 w;
        w.x = rowbuf[made_pi(4 * t + 0)];
        w.y = rowbuf[made_pi(4 * t + 1)];
        w.z = rowbuf[made_pi(4 * t + 2)];
        w.w = rowbuf[made_pi(4 * t + 3)];
        *reinterpret_cast<float4*>(o + NW0 + p * HH + 4 * t) = w;
        if (t == 0) {
            o[NW0 + NW1 + NW2 + p]      = (n ? lvb0 : mub0)[h];
            o[NW0 + NW1 + NW2 + HH + p] = (n ? lvb1 : mub1)[h];
        }
    } else {
        const int idx   = b - 512;       // 0..127
        const int n     = idx >> 6;      // net
        const int which = (idx >> 5) & 1;// 0 = W0s row, 1 = W2T row
        const int i     = idx & 31;      // row (input dim / output dim)
        float* o = ws + (size_t)n * NETF;
        if (which == 0) {
            const float* W0 = n ? lvW0 : muW0;
            *reinterpret_cast<float4*>(&rowbuf[4 * t]) =
                *reinterpret_cast<const float4*>(W0 + i * HH + 4 * t);
            __syncthreads();
            float4 w;
            w.x = rowbuf[made_pi(4 * t + 0)];
            w.y = rowbuf[made_pi(4 * t + 1)];
            w.z = rowbuf[made_pi(4 * t + 2)];
            w.w = rowbuf[made_pi(4 * t + 3)];
            *reinterpret_cast<float4*>(o + i * HH + 4 * t) = w;
        } else {
            const float* W2 = n ? lvW2 : muW2;
            float4 w;   // scattered 4B reads (stride 128B) — only 16K total, L1/L2-hit
            w.x = W2[made_pi(4 * t + 0) * DD + i];
            w.y = W2[made_pi(4 * t + 1) * DD + i];
            w.z = W2[made_pi(4 * t + 2) * DD + i];
            w.w = W2[made_pi(4 * t + 3) * DD + i];
            *reinterpret_cast<float4*>(o + NW0 + NW1 + i * HH + 4 * t) = w;
        }
    }
}

// ---------------------------------------------------------------------------
// Main: rolled d-loop (I$-resident), 4 waves/block, RR=2 rows/wave,
// wave-private LDS broadcast buffer (no barriers).
// ---------------------------------------------------------------------------
__global__ __launch_bounds__(256, 2) void made_main(
    const float* __restrict__ ws, const float* __restrict__ x,
    const float* __restrict__ mub2, const float* __restrict__ lvb2,
    float* __restrict__ out)
{
    const int lane = threadIdx.x & 63;
    const int wv   = threadIdx.x >> 6;
    const int row0 = ((blockIdx.x << 2) + wv) * RR;
    const int c4   = lane << 2;

    const float* W0p[2] = {ws,             ws + NETF};
    const float* W1p[2] = {ws + NW0,       ws + NETF + NW0};
    const float* W2p[2] = {ws + NW0 + NW1, ws + NETF + NW0 + NW1};

    float h0[2][4][RR], h1[2][4][RR], r1[2][4][RR];
    #pragma unroll
    for (int n = 0; n < 2; ++n) {
        const float* bb = ws + (size_t)n * NETF + NW0 + NW1 + NW2;
        const float4 v0 = *reinterpret_cast<const float4*>(bb + c4);
        const float4 v1 = *reinterpret_cast<const float4*>(bb + HH + c4);
        const float a0[4] = {v0.x, v0.y, v0.z, v0.w};
        const float a1[4] = {v1.x, v1.y, v1.z, v1.w};
        #pragma unroll
        for (int s = 0; s < 4; ++s)
            #pragma unroll
            for (int r = 0; r < RR; ++r) {
                h0[n][s][r] = a0[s];
                h1[n][s][r] = a1[s];
                r1[n][s][r] = 0.f;
            }
    }

    // wave-private broadcast scratch: [wave][net][row][k<=8 (pad 12)]
    __shared__ float A[4][2][RR][12];

    float yprev[RR], lsum[RR], ysave[RR];
    #pragma unroll
    for (int r = 0; r < RR; ++r) { yprev[r] = 0.f; lsum[r] = 0.f; ysave[r] = 0.f; }

    for (int d = 0; d < DD; ++d) {
        const int off  = (d >= 1) ? made_off(d) : 0;
        const int off2 = made_off(d + 1);        // OFF(d+1); d=0 -> 0
        const int nk   = off2 - off;             // 9 (d in 1..8) else 8; 0 at d=0

        if (d >= 1) {
            const int ls = off >> 2;             // first non-retired lane
            if (lane >= ls) {
                // h0 += y_{d-1} * W0s[d-1,:]
                #pragma unroll
                for (int n = 0; n < 2; ++n) {
                    const float4 w = *reinterpret_cast<const float4*>(
                        W0p[n] + (d - 1) * HH + c4);
                    #pragma unroll
                    for (int r = 0; r < RR; ++r) {
                        h0[n][0][r] = fmaf(yprev[r], w.x, h0[n][0][r]);
                        h0[n][1][r] = fmaf(yprev[r], w.y, h0[n][1][r]);
                        h0[n][2][r] = fmaf(yprev[r], w.z, h0[n][2][r]);
                        h0[n][3][r] = fmaf(yprev[r], w.w, h0[n][3][r]);
                    }
                }
            }
            // finalize h0 (positions [off,off2)) -> wave-private LDS
            #pragma unroll
            for (int s = 0; s < 4; ++s) {
                const int p = c4 + s;
                if (p >= off && p < off2) {
                    const int k = p - off;
                    #pragma unroll
                    for (int r = 0; r < RR; ++r) {
                        A[wv][0][r][k] = fmaxf(h0[0][s][r], 0.f);
                        A[wv][1][r][k] = fmaxf(h0[1][s][r], 0.f);
                    }
                }
            }
            // read broadcast values (vector reads; k=8 scalar)
            float av[2][RR][9];
            #pragma unroll
            for (int n = 0; n < 2; ++n)
                #pragma unroll
                for (int r = 0; r < RR; ++r) {
                    const float4 a03 = *reinterpret_cast<const float4*>(&A[wv][n][r][0]);
                    const float4 a47 = *reinterpret_cast<const float4*>(&A[wv][n][r][4]);
                    av[n][r][0] = a03.x; av[n][r][1] = a03.y;
                    av[n][r][2] = a03.z; av[n][r][3] = a03.w;
                    av[n][r][4] = a47.x; av[n][r][5] = a47.y;
                    av[n][r][6] = a47.z; av[n][r][7] = a47.w;
                    av[n][r][8] = A[wv][n][r][8];
                }

            if (lane >= ls) {
                // h1 += av[k] * W1s[off+k, :]
                #pragma unroll
                for (int n = 0; n < 2; ++n) {
                    const float* W1r = W1p[n] + off * HH + c4;
                    #pragma unroll
                    for (int k = 0; k < 8; ++k) {
                        const float4 w = *reinterpret_cast<const float4*>(W1r + k * HH);
                        #pragma unroll
                        for (int r = 0; r < RR; ++r) {
                            h1[n][0][r] = fmaf(av[n][r][k], w.x, h1[n][0][r]);
                            h1[n][1][r] = fmaf(av[n][r][k], w.y, h1[n][1][r]);
                            h1[n][2][r] = fmaf(av[n][r][k], w.z, h1[n][2][r]);
                            h1[n][3][r] = fmaf(av[n][r][k], w.w, h1[n][3][r]);
                        }
                    }
                }
                if (nk == 9) {
                    #pragma unroll
                    for (int n = 0; n < 2; ++n) {
                        const float4 w = *reinterpret_cast<const float4*>(
                            W1p[n] + (off + 8) * HH + c4);
                        #pragma unroll
                        for (int r = 0; r < RR; ++r) {
                            h1[n][0][r] = fmaf(av[n][r][8], w.x, h1[n][0][r]);
                            h1[n][1][r] = fmaf(av[n][r][8], w.y, h1[n][1][r]);
                            h1[n][2][r] = fmaf(av[n][r][8], w.z, h1[n][2][r]);
                            h1[n][3][r] = fmaf(av[n][r][8], w.w, h1[n][3][r]);
                        }
                    }
                }
            }
            // snapshot relu(h1) for positions finalizing now
            #pragma unroll
            for (int s = 0; s < 4; ++s) {
                const int p = c4 + s;
                if (p >= off && p < off2) {
                    #pragma unroll
                    for (int r = 0; r < RR; ++r) {
                        r1[0][s][r] = fmaxf(h1[0][s][r], 0.f);
                        r1[1][s][r] = fmaxf(h1[1][s][r], 0.f);
                    }
                }
            }
        }

        // out[d]: reduce r1 * W2T[d,:] (prefix lanes only; d=0: off2=0 -> none)
        float red[2][RR];
        #pragma unroll
        for (int n = 0; n < 2; ++n)
            #pragma unroll
            for (int r = 0; r < RR; ++r) red[n][r] = 0.f;
        if (c4 < off2) {
            #pragma unroll
            for (int n = 0; n < 2; ++n) {
                const float4 w = *reinterpret_cast<const float4*>(W2p[n] + d * HH + c4);
                #pragma unroll
                for (int r = 0; r < RR; ++r)
                    red[n][r] = fmaf(r1[n][0][r], w.x, fmaf(r1[n][1][r], w.y,
                                fmaf(r1[n][2][r], w.z, r1[n][3][r] * w.w)));
            }
        }
        #pragma unroll
        for (int m = 1; m < 64; m <<= 1)
            #pragma unroll
            for (int n = 0; n < 2; ++n)
                #pragma unroll
                for (int r = 0; r < RR; ++r)
                    red[n][r] += __shfl_xor(red[n][r], m, 64);

        const float b2m = mub2[d];   // wave-uniform scalar loads
        const float b2l = lvb2[d];
        #pragma unroll
        for (int r = 0; r < RR; ++r) {
            const float mu  = red[0][r] + b2m;
            const float ls2 = 0.5f * (red[1][r] + b2l);
            lsum[r] += ls2;
            const float yd = (x[(row0 + r) * DD + d] - mu) / (__expf(ls2) + EPSF);
            yprev[r] = yd;
            if (lane == d) ysave[r] = yd;
        }
    }

    #pragma unroll
    for (int r = 0; r < RR; ++r) {
        if (lane < DD) out[(row0 + r) * DD + lane] = ysave[r];  // coalesced
        if (lane == 0) out[BB * DD + row0 + r] = lsum[r];
    }
}

// ---------------------------------------------------------------------------
// Fallback (R1-style, no workspace) if ws is too small.
// ---------------------------------------------------------------------------
__global__ __launch_bounds__(64, 1) void made_inv_fb(
    const float* __restrict__ x,
    const float* __restrict__ muW0, const float* __restrict__ mub0,
    const float* __restrict__ muW1, const float* __restrict__ mub1,
    const float* __restrict__ muW2, const float* __restrict__ mub2,
    const float* __restrict__ lvW0, const float* __restrict__ lvb0,
    const float* __restrict__ lvW1, const float* __restrict__ lvb1,
    const float* __restrict__ lvW2, const float* __restrict__ lvb2,
    float* __restrict__ out)
{
    const int lane    = threadIdx.x;
    const int rowBase = blockIdx.x * 4;
    const int hb      = lane << 2;
    int deg[4];
    #pragma unroll
    for (int s = 0; s < 4; ++s) deg[s] = ((hb + s) % 31) + 1;
    const float* Wp0[2] = {muW0, lvW0};
    const float* Bp0[2] = {mub0, lvb0};
    const float* Wp1[2] = {muW1, lvW1};
    const float* Bp1[2] = {mub1, lvb1};
    const float* Wp2[2] = {muW2, lvW2};
    float h0pre[2][4][4], h1pre[2][4][4], r1[2][4][4], yprev[4], lsum[4];
    #pragma unroll
    for (int n = 0; n < 2; ++n) {
        const float4 b0v = *reinterpret_cast<const float4*>(Bp0[n] + hb);
        const float4 b1v = *reinterpret_cast<const float4*>(Bp1[n] + hb);
        const float b0a[4] = {b0v.x, b0v.y, b0v.z, b0v.w};
        const float b1a[4] = {b1v.x, b1v.y, b1v.z, b1v.w};
        #pragma unroll
        for (int s = 0; s < 4; ++s)
            #pragma unroll
            for (int r = 0; r < 4; ++r) {
                h0pre[n][s][r] = b0a[s]; h1pre[n][s][r] = b1a[s]; r1[n][s][r] = 0.f;
            }
    }
    #pragma unroll
    for (int r = 0; r < 4; ++r) { yprev[r] = 0.f; lsum[r] = 0.f; }
    __shared__ float lds_a[2][4][12];
    for (int d = 0; d < DD; ++d) {
        if (d >= 1) {
            #pragma unroll
            for (int n = 0; n < 2; ++n) {
                const float4 w0 = *reinterpret_cast<const float4*>(Wp0[n] + (d - 1) * HH + hb);
                const float w0a[4] = {w0.x, w0.y, w0.z, w0.w};
                #pragma unroll
                for (int s = 0; s < 4; ++s)
                    #pragma unroll
                    for (int r = 0; r < 4; ++r)
                        h0pre[n][s][r] = fmaf(yprev[r], w0a[s], h0pre[n][s][r]);
            }
            #pragma unroll
            for (int n = 0; n < 2; ++n)
                #pragma unroll
                for (int s = 0; s < 4; ++s)
                    if (deg[s] == d) {
                        const int k = (hb + s - (d - 1)) / 31;
                        #pragma unroll
                        for (int r = 0; r < 4; ++r)
                            lds_a[n][r][k] = fmaxf(h0pre[n][s][r], 0.f);
                    }
            __syncthreads();
            const bool nine = (d <= 8);
            #pragma unroll
            for (int n = 0; n < 2; ++n) {
                const float* W1r = Wp1[n] + (size_t)(d - 1) * HH + hb;
                float4 w1v[9];
                #pragma unroll
                for (int k = 0; k < 8; ++k)
                    w1v[k] = *reinterpret_cast<const float4*>(W1r + k * 31 * HH);
                if (nine) w1v[8] = *reinterpret_cast<const float4*>(W1r + 8 * 31 * HH);
                #pragma unroll
                for (int r = 0; r < 4; ++r) {
                    const float4 a03 = *reinterpret_cast<const float4*>(&lds_a[n][r][0]);
                    const float4 a47 = *reinterpret_cast<const float4*>(&lds_a[n][r][4]);
                    const float av[8] = {a03.x, a03.y, a03.z, a03.w, a47.x, a47.y, a47.z, a47.w};
                    #pragma unroll
                    for (int k = 0; k < 8; ++k) {
                        const float wk[4] = {w1v[k].x, w1v[k].y, w1v[k].z, w1v[k].w};
                        #pragma unroll
                        for (int s = 0; s < 4; ++s)
                            h1pre[n][s][r] = fmaf(av[k], wk[s], h1pre[n][s][r]);
                    }
                    if (nine) {
                        const float a8 = lds_a[n][r][8];
                        const float wk[4] = {w1v[8].x, w1v[8].y, w1v[8].z, w1v[8].w};
                        #pragma unroll
                        for (int s = 0; s < 4; ++s)
                            h1pre[n][s][r] = fmaf(a8, wk[s], h1pre[n][s][r]);
                    }
                }
            }
            #pragma unroll
            for (int n = 0; n < 2; ++n)
                #pragma unroll
                for (int s = 0; s < 4; ++s)
                    if (deg[s] == d)
                        #pragma unroll
                        for (int r = 0; r < 4; ++r)
                            r1[n][s][r] = fmaxf(h1pre[n][s][r], 0.f);
            __syncthreads();
        }
        float w2v[2][4];
        #pragma unroll
        for (int n = 0; n < 2; ++n)
            #pragma unroll
            for (int s = 0; s < 4; ++s)
                w2v[n][s] = Wp2[n][(hb + s) * DD + d];
        float red[2][4];
        #pragma unroll
        for (int n = 0; n < 2; ++n)
            #pragma unroll
            for (int r = 0; r < 4; ++r) {
                float p = 0.f;
                #pragma unroll
                for (int s = 0; s < 4; ++s) p = fmaf(r1[n][s][r], w2v[n][s], p);
                red[n][r] = p;
            }
        #pragma unroll
        for (int m = 1; m < 64; m <<= 1)
            #pragma unroll
            for (int n = 0; n < 2; ++n)
                #pragma unroll
                for (int r = 0; r < 4; ++r)
                    red[n][r] += __shfl_xor(red[n][r], m, 64);
        const float b2m = mub2[d], b2l = lvb2[d];
        #pragma unroll
        for (int r = 0; r < 4; ++r) {
            const float mu = red[0][r] + b2m;
            const float logstd = 0.5f * (red[1][r] + b2l);
            lsum[r] += logstd;
            const float yd = (x[(rowBase + r) * DD + d] - mu) / (__expf(logstd) + EPSF);
            yprev[r] = yd;
            if (lane == 0) out[(rowBase + r) * DD + d] = yd;
        }
    }
    if (lane == 0)
        #pragma unroll
        for (int r = 0; r < 4; ++r) out[BB * DD + rowBase + r] = lsum[r];
}

extern "C" void kernel_launch(void* const* d_in, const int* in_sizes, int n_in,
                              void* d_out, int out_size, void* d_ws, size_t ws_size,
                              hipStream_t stream) {
    const float* x    = (const float*)d_in[0];
    const float* muW0 = (const float*)d_in[1];
    const float* mub0 = (const float*)d_in[2];
    const float* muW1 = (const float*)d_in[3];
    const float* mub1 = (const float*)d_in[4];
    const float* muW2 = (const float*)d_in[5];
    const float* mub2 = (const float*)d_in[6];
    const float* lvW0 = (const float*)d_in[7];
    const float* lvb0 = (const float*)d_in[8];
    const float* lvW1 = (const float*)d_in[9];
    const float* lvb1 = (const float*)d_in[10];
    const float* lvW2 = (const float*)d_in[11];
    const float* lvb2 = (const float*)d_in[12];
    float* out = (float*)d_out;

    if (ws_size >= WSNEED) {
        float* ws = (float*)d_ws;
        made_prep<<<dim3(640), dim3(64), 0, stream>>>(
            muW0, mub0, muW1, mub1, muW2,
            lvW0, lvb0, lvW1, lvb1, lvW2, ws);
        made_main<<<dim3(BB / (4 * RR)), dim3(256), 0, stream>>>(ws, x, mub2, lvb2, out);
    } else {
        made_inv_fb<<<dim3(BB / 4), dim3(64), 0, stream>>>(x,
            muW0, mub0, muW1, mub1, muW2, mub2,
            lvW0, lvb0, lvW1, lvb1, lvW2, lvb2, out);
    }
}

// Round 5
// 150.954 us; speedup vs baseline: 2.2694x; 1.0817x over previous
//
#include <hip/hip_runtime.h>

#define DD   32
#define HH   256
#define BB   4096
#define RR   2      // rows per wave
#define EPSF 1e-12f

// ---------------------------------------------------------------------------
// Degree-sorted layout. deg_h[h] = (h%31)+1. Counts: deg 1..8 -> 9, 9..31 -> 8.
// Sorted position p -> original h:
//   p < 72:  h = (p/9) + 31*(p%9)
//   p >= 72: h = (8+(p-72)/8) + 31*((p-72)%8)
// Group deg==d occupies sorted positions [OFF(d), OFF(d+1)),
//   OFF(d) = (d<=9) ? 9*(d-1) : 8*d   (d>=1; OFF(1)=0, OFF(32)=256)
// ---------------------------------------------------------------------------
__device__ __forceinline__ int made_pi(int p) {
    return (p < 72) ? (p / 9) + 31 * (p % 9)
                    : (8 + (p - 72) / 8) + 31 * ((p - 72) % 8);
}
__device__ __forceinline__ int made_off(int d) {   // d >= 1
    return (d <= 9) ? 9 * (d - 1) : 8 * d;
}

// ws float layout:
//   per net n (n=0 mu, n=1 lv), base n*NETF:
//     W0s[32][256] @0 | W1s[256][256] @8192 | b0s[256] @73728 | b1s[256] @73984
//   shared W2i[256][2][32] @ 2*NETF   (W2i[p][n][dd] = Wn2[h(p)][dd])
#define NW0   (DD * HH)                 // 8192
#define NW1   (HH * HH)                 // 65536
#define NETF  (NW0 + NW1 + HH + HH)     // 74240
#define W2IOFF (2 * NETF)
#define NW2I  (HH * 64)                 // 16384
#define WSNEED ((size_t)(W2IOFF + NW2I) * 4)

// ---------------------------------------------------------------------------
// Prep: blocks 0..511 -> W1 rows (LDS-staged permute) + biases;
//       blocks 512..767 -> W2i rows; blocks 768..831 -> W0 rows.
// ---------------------------------------------------------------------------
__global__ void made_prep(
    const float* __restrict__ muW0, const float* __restrict__ mub0,
    const float* __restrict__ muW1, const float* __restrict__ mub1,
    const float* __restrict__ muW2,
    const float* __restrict__ lvW0, const float* __restrict__ lvb0,
    const float* __restrict__ lvW1, const float* __restrict__ lvb1,
    const float* __restrict__ lvW2,
    float* __restrict__ ws)
{
    const int t = threadIdx.x;           // 0..63
    const int b = blockIdx.x;
    __shared__ float rowbuf[HH];

    if (b < 512) {
        const int n = b >> 8, p = b & 255;
        const int h = made_pi(p);
        const float* W1 = n ? lvW1 : muW1;
        float* o = ws + (size_t)n * NETF;
        *reinterpret_cast<float4*>(&rowbuf[4 * t]) =
            *reinterpret_cast<const float4*>(W1 + h * HH + 4 * t);
        __syncthreads();
        float4 w;
        w.x = rowbuf[made_pi(4 * t + 0)];
        w.y = rowbuf[made_pi(4 * t + 1)];
        w.z = rowbuf[made_pi(4 * t + 2)];
        w.w = rowbuf[made_pi(4 * t + 3)];
        *reinterpret_cast<float4*>(o + NW0 + p * HH + 4 * t) = w;
        if (t == 0) {
            o[NW0 + NW1 + p]      = (n ? lvb0 : mub0)[h];
            o[NW0 + NW1 + HH + p] = (n ? lvb1 : mub1)[h];
        }
    } else if (b < 768) {
        const int p = b - 512;           // sorted position
        const int h = made_pi(p);
        const int n = t >> 5, dd = t & 31;
        ws[W2IOFF + p * 64 + t] = (n ? lvW2 : muW2)[h * DD + dd];
    } else {
        const int idx = b - 768;         // 0..63
        const int n = idx >> 5, i = idx & 31;
        const float* W0 = n ? lvW0 : muW0;
        float* o = ws + (size_t)n * NETF;
        *reinterpret_cast<float4*>(&rowbuf[4 * t]) =
            *reinterpret_cast<const float4*>(W0 + i * HH + 4 * t);
        __syncthreads();
        float4 w;
        w.x = rowbuf[made_pi(4 * t + 0)];
        w.y = rowbuf[made_pi(4 * t + 1)];
        w.z = rowbuf[made_pi(4 * t + 2)];
        w.w = rowbuf[made_pi(4 * t + 3)];
        *reinterpret_cast<float4*>(o + i * HH + 4 * t) = w;
    }
}

// ---------------------------------------------------------------------------
// Main: rolled d-loop, 4 waves/block, RR=2 rows/wave, wave-private LDS
// broadcasts, incremental per-lane output accumulators (no reduction tree).
// Lane l accumulates output (net = l>>5, dim = l&31).
// ---------------------------------------------------------------------------
__global__ __launch_bounds__(256, 2) void made_main(
    const float* __restrict__ ws, const float* __restrict__ x,
    const float* __restrict__ mub2, const float* __restrict__ lvb2,
    float* __restrict__ out)
{
    const int lane = threadIdx.x & 63;
    const int wv   = threadIdx.x >> 6;
    const int row0 = ((blockIdx.x << 2) + wv) * RR;
    const int c4   = lane << 2;          // base sorted position (4 slots/lane)
    const int nn   = lane >> 5;          // net of this lane's output acc
    const int ddl  = lane & 31;          // output dim of this lane's acc

    const float* W0p[2] = {ws,       ws + NETF};
    const float* W1p[2] = {ws + NW0, ws + NETF + NW0};
    const float* W2i    = ws + W2IOFF;

    float h0[2][4][RR], h1[2][4][RR];
    #pragma unroll
    for (int n = 0; n < 2; ++n) {
        const float* bb = ws + (size_t)n * NETF + NW0 + NW1;
        const float4 v0 = *reinterpret_cast<const float4*>(bb + c4);
        const float4 v1 = *reinterpret_cast<const float4*>(bb + HH + c4);
        const float a0[4] = {v0.x, v0.y, v0.z, v0.w};
        const float a1[4] = {v1.x, v1.y, v1.z, v1.w};
        #pragma unroll
        for (int s = 0; s < 4; ++s)
            #pragma unroll
            for (int r = 0; r < RR; ++r) { h0[n][s][r] = a0[s]; h1[n][s][r] = a1[s]; }
    }

    // output accumulators (start at b2 of this lane's (net, dim))
    const float accinit = nn ? lvb2[ddl] : mub2[ddl];
    float acc[RR];
    #pragma unroll
    for (int r = 0; r < RR; ++r) acc[r] = accinit;

    // x preload for broadcast: lane l holds x[row_r][l&31]
    float xvr[RR];
    #pragma unroll
    for (int r = 0; r < RR; ++r) xvr[r] = x[(row0 + r) * DD + ddl];

    // wave-private broadcast scratch
    __shared__ float A[4][2][RR][12];   // relu(h0) of finalizing group
    __shared__ float Bf[4][2][RR][12];  // relu(h1) of finalizing group

    float yprev[RR], lsum[RR], ysave[RR];
    #pragma unroll
    for (int r = 0; r < RR; ++r) { yprev[r] = 0.f; lsum[r] = 0.f; ysave[r] = 0.f; }

    for (int d = 0; d < DD; ++d) {
        if (d >= 1) {
            const int off  = made_off(d);
            const int off2 = made_off(d + 1);
            const int nk   = off2 - off;         // 9 (d<=8) else 8
            const int ls   = off >> 2;           // first non-retired lane

            if (lane >= ls) {
                // h0 += y_{d-1} * W0s[d-1,:]
                #pragma unroll
                for (int n = 0; n < 2; ++n) {
                    const float4 w = *reinterpret_cast<const float4*>(
                        W0p[n] + (d - 1) * HH + c4);
                    #pragma unroll
                    for (int r = 0; r < RR; ++r) {
                        h0[n][0][r] = fmaf(yprev[r], w.x, h0[n][0][r]);
                        h0[n][1][r] = fmaf(yprev[r], w.y, h0[n][1][r]);
                        h0[n][2][r] = fmaf(yprev[r], w.z, h0[n][2][r]);
                        h0[n][3][r] = fmaf(yprev[r], w.w, h0[n][3][r]);
                    }
                }
            }
            // finalize relu(h0) -> A
            #pragma unroll
            for (int s = 0; s < 4; ++s) {
                const int k = c4 + s - off;
                if ((unsigned)k < (unsigned)nk) {
                    #pragma unroll
                    for (int r = 0; r < RR; ++r) {
                        A[wv][0][r][k] = fmaxf(h0[0][s][r], 0.f);
                        A[wv][1][r][k] = fmaxf(h0[1][s][r], 0.f);
                    }
                }
            }
            // read broadcast av
            float av[2][RR][9];
            #pragma unroll
            for (int n = 0; n < 2; ++n)
                #pragma unroll
                for (int r = 0; r < RR; ++r) {
                    const float4 a03 = *reinterpret_cast<const float4*>(&A[wv][n][r][0]);
                    const float4 a47 = *reinterpret_cast<const float4*>(&A[wv][n][r][4]);
                    av[n][r][0] = a03.x; av[n][r][1] = a03.y;
                    av[n][r][2] = a03.z; av[n][r][3] = a03.w;
                    av[n][r][4] = a47.x; av[n][r][5] = a47.y;
                    av[n][r][6] = a47.z; av[n][r][7] = a47.w;
                    av[n][r][8] = A[wv][n][r][8];
                }

            if (lane >= ls) {
                // h1 += av[k] * W1s[off+k, :]
                #pragma unroll
                for (int n = 0; n < 2; ++n) {
                    const float* W1r = W1p[n] + off * HH + c4;
                    #pragma unroll
                    for (int k = 0; k < 8; ++k) {
                        const float4 w = *reinterpret_cast<const float4*>(W1r + k * HH);
                        #pragma unroll
                        for (int r = 0; r < RR; ++r) {
                            h1[n][0][r] = fmaf(av[n][r][k], w.x, h1[n][0][r]);
                            h1[n][1][r] = fmaf(av[n][r][k], w.y, h1[n][1][r]);
                            h1[n][2][r] = fmaf(av[n][r][k], w.z, h1[n][2][r]);
                            h1[n][3][r] = fmaf(av[n][r][k], w.w, h1[n][3][r]);
                        }
                    }
                }
                if (d <= 8) {
                    #pragma unroll
                    for (int n = 0; n < 2; ++n) {
                        const float4 w = *reinterpret_cast<const float4*>(
                            W1p[n] + (off + 8) * HH + c4);
                        #pragma unroll
                        for (int r = 0; r < RR; ++r) {
                            h1[n][0][r] = fmaf(av[n][r][8], w.x, h1[n][0][r]);
                            h1[n][1][r] = fmaf(av[n][r][8], w.y, h1[n][1][r]);
                            h1[n][2][r] = fmaf(av[n][r][8], w.z, h1[n][2][r]);
                            h1[n][3][r] = fmaf(av[n][r][8], w.w, h1[n][3][r]);
                        }
                    }
                }
            }
            // finalize relu(h1) -> Bf
            #pragma unroll
            for (int s = 0; s < 4; ++s) {
                const int k = c4 + s - off;
                if ((unsigned)k < (unsigned)nk) {
                    #pragma unroll
                    for (int r = 0; r < RR; ++r) {
                        Bf[wv][0][r][k] = fmaxf(h1[0][s][r], 0.f);
                        Bf[wv][1][r][k] = fmaxf(h1[1][s][r], 0.f);
                    }
                }
            }
            // read r1 broadcast for this lane's net, fold into output accs
            float rb[RR][9];
            #pragma unroll
            for (int r = 0; r < RR; ++r) {
                const float4 b03 = *reinterpret_cast<const float4*>(&Bf[wv][nn][r][0]);
                const float4 b47 = *reinterpret_cast<const float4*>(&Bf[wv][nn][r][4]);
                rb[r][0] = b03.x; rb[r][1] = b03.y; rb[r][2] = b03.z; rb[r][3] = b03.w;
                rb[r][4] = b47.x; rb[r][5] = b47.y; rb[r][6] = b47.z; rb[r][7] = b47.w;
                rb[r][8] = Bf[wv][nn][r][8];
            }
            const float* w2c = W2i + off * 64 + lane;
            #pragma unroll
            for (int k = 0; k < 8; ++k) {
                const float w2 = w2c[k * 64];
                #pragma unroll
                for (int r = 0; r < RR; ++r)
                    acc[r] = fmaf(rb[r][k], w2, acc[r]);
            }
            if (d <= 8) {
                const float w2 = w2c[8 * 64];
                #pragma unroll
                for (int r = 0; r < RR; ++r)
                    acc[r] = fmaf(rb[r][8], w2, acc[r]);
            }
        }

        // outputs for dim d: pull acc from lanes d (mu) and 32+d (lv)
        #pragma unroll
        for (int r = 0; r < RR; ++r) {
            const float mu  = __shfl(acc[r], d, 64);
            const float lv  = __shfl(acc[r], 32 + d, 64);
            const float ls2 = 0.5f * lv;
            lsum[r] += ls2;
            const float yd = (__shfl(xvr[r], d, 64) - mu) / (__expf(ls2) + EPSF);
            yprev[r] = yd;
            if (lane == d) ysave[r] = yd;
        }
    }

    #pragma unroll
    for (int r = 0; r < RR; ++r) {
        if (lane < DD) out[(row0 + r) * DD + lane] = ysave[r];   // coalesced
        if (lane == 0) out[BB * DD + row0 + r] = lsum[r];
    }
}

// ---------------------------------------------------------------------------
// Fallback (no workspace): R1-style kernel.
// ---------------------------------------------------------------------------
__global__ __launch_bounds__(64, 1) void made_inv_fb(
    const float* __restrict__ x,
    const float* __restrict__ muW0, const float* __restrict__ mub0,
    const float* __restrict__ muW1, const float* __restrict__ mub1,
    const float* __restrict__ muW2, const float* __restrict__ mub2,
    const float* __restrict__ lvW0, const float* __restrict__ lvb0,
    const float* __restrict__ lvW1, const float* __restrict__ lvb1,
    const float* __restrict__ lvW2, const float* __restrict__ lvb2,
    float* __restrict__ out)
{
    const int lane    = threadIdx.x;
    const int rowBase = blockIdx.x * 4;
    const int hb      = lane << 2;
    int deg[4];
    #pragma unroll
    for (int s = 0; s < 4; ++s) deg[s] = ((hb + s) % 31) + 1;
    const float* Wp0[2] = {muW0, lvW0};
    const float* Bp0[2] = {mub0, lvb0};
    const float* Wp1[2] = {muW1, lvW1};
    const float* Bp1[2] = {mub1, lvb1};
    const float* Wp2[2] = {muW2, lvW2};
    float h0pre[2][4][4], h1pre[2][4][4], r1[2][4][4], yprev[4], lsum[4];
    #pragma unroll
    for (int n = 0; n < 2; ++n) {
        const float4 b0v = *reinterpret_cast<const float4*>(Bp0[n] + hb);
        const float4 b1v = *reinterpret_cast<const float4*>(Bp1[n] + hb);
        const float b0a[4] = {b0v.x, b0v.y, b0v.z, b0v.w};
        const float b1a[4] = {b1v.x, b1v.y, b1v.z, b1v.w};
        #pragma unroll
        for (int s = 0; s < 4; ++s)
            #pragma unroll
            for (int r = 0; r < 4; ++r) {
                h0pre[n][s][r] = b0a[s]; h1pre[n][s][r] = b1a[s]; r1[n][s][r] = 0.f;
            }
    }
    #pragma unroll
    for (int r = 0; r < 4; ++r) { yprev[r] = 0.f; lsum[r] = 0.f; }
    __shared__ float lds_a[2][4][12];
    for (int d = 0; d < DD; ++d) {
        if (d >= 1) {
            #pragma unroll
            for (int n = 0; n < 2; ++n) {
                const float4 w0 = *reinterpret_cast<const float4*>(Wp0[n] + (d - 1) * HH + hb);
                const float w0a[4] = {w0.x, w0.y, w0.z, w0.w};
                #pragma unroll
                for (int s = 0; s < 4; ++s)
                    #pragma unroll
                    for (int r = 0; r < 4; ++r)
                        h0pre[n][s][r] = fmaf(yprev[r], w0a[s], h0pre[n][s][r]);
            }
            #pragma unroll
            for (int n = 0; n < 2; ++n)
                #pragma unroll
                for (int s = 0; s < 4; ++s)
                    if (deg[s] == d) {
                        const int k = (hb + s - (d - 1)) / 31;
                        #pragma unroll
                        for (int r = 0; r < 4; ++r)
                            lds_a[n][r][k] = fmaxf(h0pre[n][s][r], 0.f);
                    }
            __syncthreads();
            const bool nine = (d <= 8);
            #pragma unroll
            for (int n = 0; n < 2; ++n) {
                const float* W1r = Wp1[n] + (size_t)(d - 1) * HH + hb;
                float4 w1v[9];
                #pragma unroll
                for (int k = 0; k < 8; ++k)
                    w1v[k] = *reinterpret_cast<const float4*>(W1r + k * 31 * HH);
                if (nine) w1v[8] = *reinterpret_cast<const float4*>(W1r + 8 * 31 * HH);
                #pragma unroll
                for (int r = 0; r < 4; ++r) {
                    const float4 a03 = *reinterpret_cast<const float4*>(&lds_a[n][r][0]);
                    const float4 a47 = *reinterpret_cast<const float4*>(&lds_a[n][r][4]);
                    const float av[8] = {a03.x, a03.y, a03.z, a03.w, a47.x, a47.y, a47.z, a47.w};
                    #pragma unroll
                    for (int k = 0; k < 8; ++k) {
                        const float wk[4] = {w1v[k].x, w1v[k].y, w1v[k].z, w1v[k].w};
                        #pragma unroll
                        for (int s = 0; s < 4; ++s)
                            h1pre[n][s][r] = fmaf(av[k], wk[s], h1pre[n][s][r]);
                    }
                    if (nine) {
                        const float a8 = lds_a[n][r][8];
                        const float wk[4] = {w1v[8].x, w1v[8].y, w1v[8].z, w1v[8].w};
                        #pragma unroll
                        for (int s = 0; s < 4; ++s)
                            h1pre[n][s][r] = fmaf(a8, wk[s], h1pre[n][s][r]);
                    }
                }
            }
            #pragma unroll
            for (int n = 0; n < 2; ++n)
                #pragma unroll
                for (int s = 0; s < 4; ++s)
                    if (deg[s] == d)
                        #pragma unroll
                        for (int r = 0; r < 4; ++r)
                            r1[n][s][r] = fmaxf(h1pre[n][s][r], 0.f);
            __syncthreads();
        }
        float w2v[2][4];
        #pragma unroll
        for (int n = 0; n < 2; ++n)
            #pragma unroll
            for (int s = 0; s < 4; ++s)
                w2v[n][s] = Wp2[n][(hb + s) * DD + d];
        float red[2][4];
        #pragma unroll
        for (int n = 0; n < 2; ++n)
            #pragma unroll
            for (int r = 0; r < 4; ++r) {
                float p = 0.f;
                #pragma unroll
                for (int s = 0; s < 4; ++s) p = fmaf(r1[n][s][r], w2v[n][s], p);
                red[n][r] = p;
            }
        #pragma unroll
        for (int m = 1; m < 64; m <<= 1)
            #pragma unroll
            for (int n = 0; n < 2; ++n)
                #pragma unroll
                for (int r = 0; r < 4; ++r)
                    red[n][r] += __shfl_xor(red[n][r], m, 64);
        const float b2m = mub2[d], b2l = lvb2[d];
        #pragma unroll
        for (int r = 0; r < 4; ++r) {
            const float mu = red[0][r] + b2m;
            const float logstd = 0.5f * (red[1][r] + b2l);
            lsum[r] += logstd;
            const float yd = (x[(rowBase + r) * DD + d] - mu) / (__expf(logstd) + EPSF);
            yprev[r] = yd;
            if (lane == 0) out[(rowBase + r) * DD + d] = yd;
        }
    }
    if (lane == 0)
        #pragma unroll
        for (int r = 0; r < 4; ++r) out[BB * DD + rowBase + r] = lsum[r];
}

extern "C" void kernel_launch(void* const* d_in, const int* in_sizes, int n_in,
                              void* d_out, int out_size, void* d_ws, size_t ws_size,
                              hipStream_t stream) {
    const float* x    = (const float*)d_in[0];
    const float* muW0 = (const float*)d_in[1];
    const float* mub0 = (const float*)d_in[2];
    const float* muW1 = (const float*)d_in[3];
    const float* mub1 = (const float*)d_in[4];
    const float* muW2 = (const float*)d_in[5];
    const float* mub2 = (const float*)d_in[6];
    const float* lvW0 = (const float*)d_in[7];
    const float* lvb0 = (const float*)d_in[8];
    const float* lvW1 = (const float*)d_in[9];
    const float* lvb1 = (const float*)d_in[10];
    const float* lvW2 = (const float*)d_in[11];
    const float* lvb2 = (const float*)d_in[12];
    float* out = (float*)d_out;

    if (ws_size >= WSNEED) {
        float* ws = (float*)d_ws;
        made_prep<<<dim3(832), dim3(64), 0, stream>>>(
            muW0, mub0, muW1, mub1, muW2,
            lvW0, lvb0, lvW1, lvb1, lvW2, ws);
        made_main<<<dim3(BB / (4 * RR)), dim3(256), 0, stream>>>(ws, x, mub2, lvb2, out);
    } else {
        made_inv_fb<<<dim3(BB / 4), dim3(64), 0, stream>>>(x,
            muW0, mub0, muW1, mub1, muW2, mub2,
            lvW0, lvb0, lvW1, lvb1, lvW2, lvb2, out);
    }
}

// Round 7
// 135.897 us; speedup vs baseline: 2.5208x; 1.1108x over previous
//
#include <hip/hip_runtime.h>

#define DD   32
#define HH   256
#define BB   4096
#define RR   2      // rows per wave
#define EPSF 1e-12f

// ---------------------------------------------------------------------------
// Degree-sorted layout. deg_h[h] = (h%31)+1. Counts: deg 1..8 -> 9, 9..31 -> 8.
// Sorted position p -> original h:
//   p < 72:  h = (p/9) + 31*(p%9)
//   p >= 72: h = (8+(p-72)/8) + 31*((p-72)%8)
// Group deg==d occupies sorted positions [OFF(d), OFF(d+1)),
//   OFF(d) = (d<=9) ? 9*(d-1) : 8*d   (d>=1; OFF(1)=0, OFF(32)=256)
// ---------------------------------------------------------------------------
__device__ __forceinline__ int made_pi(int p) {
    return (p < 72) ? (p / 9) + 31 * (p % 9)
                    : (8 + (p - 72) / 8) + 31 * ((p - 72) % 8);
}
__device__ __forceinline__ int made_off(int d) {   // d >= 1
    return (d <= 9) ? 9 * (d - 1) : 8 * d;
}

// ws float layout:
//   per net n (n=0 mu, n=1 lv), base n*NETF:
//     W0s[32][256] @0 | W1s[256][256] @8192 | b0s[256] @73728 | b1s[256] @73984
//   shared W2i[256][2][32] @ 2*NETF   (W2i[p][n][dd] = Wn2[h(p)][dd])
#define NW0   (DD * HH)                 // 8192
#define NW1   (HH * HH)                 // 65536
#define NETF  (NW0 + NW1 + HH + HH)     // 74240
#define W2IOFF (2 * NETF)
#define NW2I  (HH * 64)                 // 16384
#define WSNEED ((size_t)(W2IOFF + NW2I) * 4)

// ---------------------------------------------------------------------------
// Prep: blocks 0..511 -> W1 rows (LDS-staged permute) + biases;
//       blocks 512..767 -> W2i rows; blocks 768..831 -> W0 rows.
// ---------------------------------------------------------------------------
__global__ void made_prep(
    const float* __restrict__ muW0, const float* __restrict__ mub0,
    const float* __restrict__ muW1, const float* __restrict__ mub1,
    const float* __restrict__ muW2,
    const float* __restrict__ lvW0, const float* __restrict__ lvb0,
    const float* __restrict__ lvW1, const float* __restrict__ lvb1,
    const float* __restrict__ lvW2,
    float* __restrict__ ws)
{
    const int t = threadIdx.x;           // 0..63
    const int b = blockIdx.x;
    __shared__ float rowbuf[HH];

    if (b < 512) {
        const int n = b >> 8, p = b & 255;
        const int h = made_pi(p);
        const float* W1 = n ? lvW1 : muW1;
        float* o = ws + (size_t)n * NETF;
        *reinterpret_cast<float4*>(&rowbuf[4 * t]) =
            *reinterpret_cast<const float4*>(W1 + h * HH + 4 * t);
        __syncthreads();
        float4 w;
        w.x = rowbuf[made_pi(4 * t + 0)];
        w.y = rowbuf[made_pi(4 * t + 1)];
        w.z = rowbuf[made_pi(4 * t + 2)];
        w.w = rowbuf[made_pi(4 * t + 3)];
        *reinterpret_cast<float4*>(o + NW0 + p * HH + 4 * t) = w;
        if (t == 0) {
            o[NW0 + NW1 + p]      = (n ? lvb0 : mub0)[h];
            o[NW0 + NW1 + HH + p] = (n ? lvb1 : mub1)[h];
        }
    } else if (b < 768) {
        const int p = b - 512;           // sorted position
        const int h = made_pi(p);
        const int n = t >> 5, dd = t & 31;
        ws[W2IOFF + p * 64 + t] = (n ? lvW2 : muW2)[h * DD + dd];
    } else {
        const int idx = b - 768;         // 0..63
        const int n = idx >> 5, i = idx & 31;
        const float* W0 = n ? lvW0 : muW0;
        float* o = ws + (size_t)n * NETF;
        *reinterpret_cast<float4*>(&rowbuf[4 * t]) =
            *reinterpret_cast<const float4*>(W0 + i * HH + 4 * t);
        __syncthreads();
        float4 w;
        w.x = rowbuf[made_pi(4 * t + 0)];
        w.y = rowbuf[made_pi(4 * t + 1)];
        w.z = rowbuf[made_pi(4 * t + 2)];
        w.w = rowbuf[made_pi(4 * t + 3)];
        *reinterpret_cast<float4*>(o + i * HH + 4 * t) = w;
    }
}

// ---------------------------------------------------------------------------
// Main: rolled d-loop, 4 waves/block, RR=2 rows/wave, wave-private LDS
// broadcasts, incremental per-lane output accumulators.
// R7 = R6 fixed: finalize writes use k < nk (NOT k < 9) so the lane owning
// position off+8 (next group, d>=9) cannot clobber the zeroed slot 8.
// Branch-free h0/h1/acc updates; uniform 9-FMA groups (slot 8 zero for d>=9,
// 9th row index clamped); all global loads burst-issued at step top.
// ---------------------------------------------------------------------------
__global__ __launch_bounds__(256, 2) void made_main(
    const float* __restrict__ ws, const float* __restrict__ x,
    const float* __restrict__ mub2, const float* __restrict__ lvb2,
    float* __restrict__ out)
{
    const int lane = threadIdx.x & 63;
    const int wv   = threadIdx.x >> 6;
    const int row0 = ((blockIdx.x << 2) + wv) * RR;
    const int c4   = lane << 2;          // base sorted position (4 slots/lane)
    const int nn   = lane >> 5;          // net of this lane's output acc
    const int ddl  = lane & 31;          // output dim of this lane's acc

    const float* W0p[2] = {ws,       ws + NETF};
    const float* W1p[2] = {ws + NW0, ws + NETF + NW0};
    const float* W2i    = ws + W2IOFF;

    float h0[2][4][RR], h1[2][4][RR];
    #pragma unroll
    for (int n = 0; n < 2; ++n) {
        const float* bb = ws + (size_t)n * NETF + NW0 + NW1;
        const float4 v0 = *reinterpret_cast<const float4*>(bb + c4);
        const float4 v1 = *reinterpret_cast<const float4*>(bb + HH + c4);
        const float a0[4] = {v0.x, v0.y, v0.z, v0.w};
        const float a1[4] = {v1.x, v1.y, v1.z, v1.w};
        #pragma unroll
        for (int s = 0; s < 4; ++s)
            #pragma unroll
            for (int r = 0; r < RR; ++r) { h0[n][s][r] = a0[s]; h1[n][s][r] = a1[s]; }
    }

    // output accumulators (start at b2 of this lane's (net, dim))
    const float accinit = nn ? lvb2[ddl] : mub2[ddl];
    float acc[RR];
    #pragma unroll
    for (int r = 0; r < RR; ++r) acc[r] = accinit;

    // x preload for broadcast: lane l holds x[row_r][l&31]
    float xvr[RR];
    #pragma unroll
    for (int r = 0; r < RR; ++r) xvr[r] = x[(row0 + r) * DD + ddl];

    // wave-private broadcast scratch
    __shared__ float A[4][2][RR][12];   // relu(h0) of finalizing group
    __shared__ float Bf[4][2][RR][12];  // relu(h1) of finalizing group

    float yprev[RR], lsum[RR], ysave[RR];
    #pragma unroll
    for (int r = 0; r < RR; ++r) { lsum[r] = 0.f; ysave[r] = 0.f; }

    // ---- step d = 0: no hidden unit finalized yet; acc == b2
    #pragma unroll
    for (int r = 0; r < RR; ++r) {
        const float mu  = __shfl(acc[r], 0, 64);
        const float lv  = __shfl(acc[r], 32, 64);
        const float ls2 = 0.5f * lv;
        lsum[r] += ls2;
        const float yd = (__shfl(xvr[r], 0, 64) - mu) / (__expf(ls2) + EPSF);
        yprev[r] = yd;
        if (lane == 0) ysave[r] = yd;
    }

    for (int d = 1; d < DD; ++d) {
        const int off = made_off(d);
        const int nk  = (d <= 8) ? 9 : 8;           // group size
        int r8 = off + 8; if (r8 > 255) r8 = 255;   // clamped 9th row (x0 for d>=9)

        // ================= burst-issue ALL global loads for this step ======
        const float4 w0m = *reinterpret_cast<const float4*>(W0p[0] + (d - 1) * HH + c4);
        const float4 w0l = *reinterpret_cast<const float4*>(W0p[1] + (d - 1) * HH + c4);
        float4 w1m[9], w1l[9];
        {
            const float* a = W1p[0] + off * HH + c4;
            const float* b = W1p[1] + off * HH + c4;
            #pragma unroll
            for (int k = 0; k < 8; ++k) {
                w1m[k] = *reinterpret_cast<const float4*>(a + k * HH);
                w1l[k] = *reinterpret_cast<const float4*>(b + k * HH);
            }
            w1m[8] = *reinterpret_cast<const float4*>(W1p[0] + r8 * HH + c4);
            w1l[8] = *reinterpret_cast<const float4*>(W1p[1] + r8 * HH + c4);
        }
        float w2[9];
        {
            const float* w2c = W2i + off * 64 + lane;
            #pragma unroll
            for (int k = 0; k < 8; ++k) w2[k] = w2c[k * 64];
            w2[8] = W2i[r8 * 64 + lane];
        }

        // ================= h0 += y_{d-1} * W0s[d-1,:] (all lanes) ==========
        #pragma unroll
        for (int r = 0; r < RR; ++r) {
            h0[0][0][r] = fmaf(yprev[r], w0m.x, h0[0][0][r]);
            h0[0][1][r] = fmaf(yprev[r], w0m.y, h0[0][1][r]);
            h0[0][2][r] = fmaf(yprev[r], w0m.z, h0[0][2][r]);
            h0[0][3][r] = fmaf(yprev[r], w0m.w, h0[0][3][r]);
            h0[1][0][r] = fmaf(yprev[r], w0l.x, h0[1][0][r]);
            h0[1][1][r] = fmaf(yprev[r], w0l.y, h0[1][1][r]);
            h0[1][2][r] = fmaf(yprev[r], w0l.z, h0[1][2][r]);
            h0[1][3][r] = fmaf(yprev[r], w0l.w, h0[1][3][r]);
        }

        // zero the k=8 broadcast slots when the group has only 8 members
        // (persists: finalize writes below are bounded by nk=8 for d>=9)
        if (d >= 9 && lane == 0) {
            #pragma unroll
            for (int n = 0; n < 2; ++n)
                #pragma unroll
                for (int r = 0; r < RR; ++r) {
                    A[wv][n][r][8]  = 0.f;
                    Bf[wv][n][r][8] = 0.f;
                }
        }
        // finalize relu(h0) -> A (ONLY the nk members of group d)
        #pragma unroll
        for (int s = 0; s < 4; ++s) {
            const int k = c4 + s - off;
            if ((unsigned)k < (unsigned)nk) {
                #pragma unroll
                for (int r = 0; r < RR; ++r) {
                    A[wv][0][r][k] = fmaxf(h0[0][s][r], 0.f);
                    A[wv][1][r][k] = fmaxf(h0[1][s][r], 0.f);
                }
            }
        }
        // read broadcast av (wave-private LDS; program order guarantees vis.)
        float av[2][RR][9];
        #pragma unroll
        for (int n = 0; n < 2; ++n)
            #pragma unroll
            for (int r = 0; r < RR; ++r) {
                const float4 a03 = *reinterpret_cast<const float4*>(&A[wv][n][r][0]);
                const float4 a47 = *reinterpret_cast<const float4*>(&A[wv][n][r][4]);
                av[n][r][0] = a03.x; av[n][r][1] = a03.y;
                av[n][r][2] = a03.z; av[n][r][3] = a03.w;
                av[n][r][4] = a47.x; av[n][r][5] = a47.y;
                av[n][r][6] = a47.z; av[n][r][7] = a47.w;
                av[n][r][8] = A[wv][n][r][8];
            }

        // ================= h1 += av[k] * W1s[row k] — uniform 9 ============
        #pragma unroll
        for (int k = 0; k < 9; ++k) {
            #pragma unroll
            for (int r = 0; r < RR; ++r) {
                h1[0][0][r] = fmaf(av[0][r][k], w1m[k].x, h1[0][0][r]);
                h1[0][1][r] = fmaf(av[0][r][k], w1m[k].y, h1[0][1][r]);
                h1[0][2][r] = fmaf(av[0][r][k], w1m[k].z, h1[0][2][r]);
                h1[0][3][r] = fmaf(av[0][r][k], w1m[k].w, h1[0][3][r]);
                h1[1][0][r] = fmaf(av[1][r][k], w1l[k].x, h1[1][0][r]);
                h1[1][1][r] = fmaf(av[1][r][k], w1l[k].y, h1[1][1][r]);
                h1[1][2][r] = fmaf(av[1][r][k], w1l[k].z, h1[1][2][r]);
                h1[1][3][r] = fmaf(av[1][r][k], w1l[k].w, h1[1][3][r]);
            }
        }

        // finalize relu(h1) -> Bf (ONLY the nk members of group d)
        #pragma unroll
        for (int s = 0; s < 4; ++s) {
            const int k = c4 + s - off;
            if ((unsigned)k < (unsigned)nk) {
                #pragma unroll
                for (int r = 0; r < RR; ++r) {
                    Bf[wv][0][r][k] = fmaxf(h1[0][s][r], 0.f);
                    Bf[wv][1][r][k] = fmaxf(h1[1][s][r], 0.f);
                }
            }
        }
        // read r1 broadcast for this lane's net, fold into output accs
        float rb[RR][9];
        #pragma unroll
        for (int r = 0; r < RR; ++r) {
            const float4 b03 = *reinterpret_cast<const float4*>(&Bf[wv][nn][r][0]);
            const float4 b47 = *reinterpret_cast<const float4*>(&Bf[wv][nn][r][4]);
            rb[r][0] = b03.x; rb[r][1] = b03.y; rb[r][2] = b03.z; rb[r][3] = b03.w;
            rb[r][4] = b47.x; rb[r][5] = b47.y; rb[r][6] = b47.z; rb[r][7] = b47.w;
            rb[r][8] = Bf[wv][nn][r][8];
        }
        #pragma unroll
        for (int k = 0; k < 9; ++k)
            #pragma unroll
            for (int r = 0; r < RR; ++r)
                acc[r] = fmaf(rb[r][k], w2[k], acc[r]);

        // ================= outputs for dim d ===============================
        #pragma unroll
        for (int r = 0; r < RR; ++r) {
            const float mu  = __shfl(acc[r], d, 64);
            const float lv  = __shfl(acc[r], 32 + d, 64);
            const float ls2 = 0.5f * lv;
            lsum[r] += ls2;
            const float yd = (__shfl(xvr[r], d, 64) - mu) / (__expf(ls2) + EPSF);
            yprev[r] = yd;
            if (lane == d) ysave[r] = yd;
        }
    }

    #pragma unroll
    for (int r = 0; r < RR; ++r) {
        if (lane < DD) out[(row0 + r) * DD + lane] = ysave[r];   // coalesced
        if (lane == 0) out[BB * DD + row0 + r] = lsum[r];
    }
}

// ---------------------------------------------------------------------------
// Fallback (no workspace): R1-style kernel.
// ---------------------------------------------------------------------------
__global__ __launch_bounds__(64, 1) void made_inv_fb(
    const float* __restrict__ x,
    const float* __restrict__ muW0, const float* __restrict__ mub0,
    const float* __restrict__ muW1, const float* __restrict__ mub1,
    const float* __restrict__ muW2, const float* __restrict__ mub2,
    const float* __restrict__ lvW0, const float* __restrict__ lvb0,
    const float* __restrict__ lvW1, const float* __restrict__ lvb1,
    const float* __restrict__ lvW2, const float* __restrict__ lvb2,
    float* __restrict__ out)
{
    const int lane    = threadIdx.x;
    const int rowBase = blockIdx.x * 4;
    const int hb      = lane << 2;
    int deg[4];
    #pragma unroll
    for (int s = 0; s < 4; ++s) deg[s] = ((hb + s) % 31) + 1;
    const float* Wp0[2] = {muW0, lvW0};
    const float* Bp0[2] = {mub0, lvb0};
    const float* Wp1[2] = {muW1, lvW1};
    const float* Bp1[2] = {mub1, lvb1};
    const float* Wp2[2] = {muW2, lvW2};
    float h0pre[2][4][4], h1pre[2][4][4], r1[2][4][4], yprev[4], lsum[4];
    #pragma unroll
    for (int n = 0; n < 2; ++n) {
        const float4 b0v = *reinterpret_cast<const float4*>(Bp0[n] + hb);
        const float4 b1v = *reinterpret_cast<const float4*>(Bp1[n] + hb);
        const float b0a[4] = {b0v.x, b0v.y, b0v.z, b0v.w};
        const float b1a[4] = {b1v.x, b1v.y, b1v.z, b1v.w};
        #pragma unroll
        for (int s = 0; s < 4; ++s)
            #pragma unroll
            for (int r = 0; r < 4; ++r) {
                h0pre[n][s][r] = b0a[s]; h1pre[n][s][r] = b1a[s]; r1[n][s][r] = 0.f;
            }
    }
    #pragma unroll
    for (int r = 0; r < 4; ++r) { yprev[r] = 0.f; lsum[r] = 0.f; }
    __shared__ float lds_a[2][4][12];
    for (int d = 0; d < DD; ++d) {
        if (d >= 1) {
            #pragma unroll
            for (int n = 0; n < 2; ++n) {
                const float4 w0 = *reinterpret_cast<const float4*>(Wp0[n] + (d - 1) * HH + hb);
                const float w0a[4] = {w0.x, w0.y, w0.z, w0.w};
                #pragma unroll
                for (int s = 0; s < 4; ++s)
                    #pragma unroll
                    for (int r = 0; r < 4; ++r)
                        h0pre[n][s][r] = fmaf(yprev[r], w0a[s], h0pre[n][s][r]);
            }
            #pragma unroll
            for (int n = 0; n < 2; ++n)
                #pragma unroll
                for (int s = 0; s < 4; ++s)
                    if (deg[s] == d) {
                        const int k = (hb + s - (d - 1)) / 31;
                        #pragma unroll
                        for (int r = 0; r < 4; ++r)
                            lds_a[n][r][k] = fmaxf(h0pre[n][s][r], 0.f);
                    }
            __syncthreads();
            const bool nine = (d <= 8);
            #pragma unroll
            for (int n = 0; n < 2; ++n) {
                const float* W1r = Wp1[n] + (size_t)(d - 1) * HH + hb;
                float4 w1v[9];
                #pragma unroll
                for (int k = 0; k < 8; ++k)
                    w1v[k] = *reinterpret_cast<const float4*>(W1r + k * 31 * HH);
                if (nine) w1v[8] = *reinterpret_cast<const float4*>(W1r + 8 * 31 * HH);
                #pragma unroll
                for (int r = 0; r < 4; ++r) {
                    const float4 a03 = *reinterpret_cast<const float4*>(&lds_a[n][r][0]);
                    const float4 a47 = *reinterpret_cast<const float4*>(&lds_a[n][r][4]);
                    const float av[8] = {a03.x, a03.y, a03.z, a03.w, a47.x, a47.y, a47.z, a47.w};
                    #pragma unroll
                    for (int k = 0; k < 8; ++k) {
                        const float wk[4] = {w1v[k].x, w1v[k].y, w1v[k].z, w1v[k].w};
                        #pragma unroll
                        for (int s = 0; s < 4; ++s)
                            h1pre[n][s][r] = fmaf(av[k], wk[s], h1pre[n][s][r]);
                    }
                    if (nine) {
                        const float a8 = lds_a[n][r][8];
                        const float wk[4] = {w1v[8].x, w1v[8].y, w1v[8].z, w1v[8].w};
                        #pragma unroll
                        for (int s = 0; s < 4; ++s)
                            h1pre[n][s][r] = fmaf(a8, wk[s], h1pre[n][s][r]);
                    }
                }
            }
            #pragma unroll
            for (int n = 0; n < 2; ++n)
                #pragma unroll
                for (int s = 0; s < 4; ++s)
                    if (deg[s] == d)
                        #pragma unroll
                        for (int r = 0; r < 4; ++r)
                            r1[n][s][r] = fmaxf(h1pre[n][s][r], 0.f);
            __syncthreads();
        }
        float w2v[2][4];
        #pragma unroll
        for (int n = 0; n < 2; ++n)
            #pragma unroll
            for (int s = 0; s < 4; ++s)
                w2v[n][s] = Wp2[n][(hb + s) * DD + d];
        float red[2][4];
        #pragma unroll
        for (int n = 0; n < 2; ++n)
            #pragma unroll
            for (int r = 0; r < 4; ++r) {
                float p = 0.f;
                #pragma unroll
                for (int s = 0; s < 4; ++s) p = fmaf(r1[n][s][r], w2v[n][s], p);
                red[n][r] = p;
            }
        #pragma unroll
        for (int m = 1; m < 64; m <<= 1)
            #pragma unroll
            for (int n = 0; n < 2; ++n)
                #pragma unroll
                for (int r = 0; r < 4; ++r)
                    red[n][r] += __shfl_xor(red[n][r], m, 64);
        const float b2m = mub2[d], b2l = lvb2[d];
        #pragma unroll
        for (int r = 0; r < 4; ++r) {
            const float mu = red[0][r] + b2m;
            const float logstd = 0.5f * (red[1][r] + b2l);
            lsum[r] += logstd;
            const float yd = (x[(rowBase + r) * DD + d] - mu) / (__expf(logstd) + EPSF);
            yprev[r] = yd;
            if (lane == 0) out[(rowBase + r) * DD + d] = yd;
        }
    }
    if (lane == 0)
        #pragma unroll
        for (int r = 0; r < 4; ++r) out[BB * DD + rowBase + r] = lsum[r];
}

extern "C" void kernel_launch(void* const* d_in, const int* in_sizes, int n_in,
                              void* d_out, int out_size, void* d_ws, size_t ws_size,
                              hipStream_t stream) {
    const float* x    = (const float*)d_in[0];
    const float* muW0 = (const float*)d_in[1];
    const float* mub0 = (const float*)d_in[2];
    const float* muW1 = (const float*)d_in[3];
    const float* mub1 = (const float*)d_in[4];
    const float* muW2 = (const float*)d_in[5];
    const float* mub2 = (const float*)d_in[6];
    const float* lvW0 = (const float*)d_in[7];
    const float* lvb0 = (const float*)d_in[8];
    const float* lvW1 = (const float*)d_in[9];
    const float* lvb1 = (const float*)d_in[10];
    const float* lvW2 = (const float*)d_in[11];
    const float* lvb2 = (const float*)d_in[12];
    float* out = (float*)d_out;

    if (ws_size >= WSNEED) {
        float* ws = (float*)d_ws;
        made_prep<<<dim3(832), dim3(64), 0, stream>>>(
            muW0, mub0, muW1, mub1, muW2,
            lvW0, lvb0, lvW1, lvb1, lvW2, ws);
        made_main<<<dim3(BB / (4 * RR)), dim3(256), 0, stream>>>(ws, x, mub2, lvb2, out);
    } else {
        made_inv_fb<<<dim3(BB / 4), dim3(64), 0, stream>>>(x,
            muW0, mub0, muW1, mub1, muW2, mub2,
            lvW0, lvb0, lvW1, lvb1, lvW2, lvb2, out);
    }
}